// Round 9
// baseline (1116.571 us; speedup 1.0000x reference)
//
#include <hip/hip_runtime.h>
#include <hip/hip_bf16.h>
#include <cstddef>

#define THREADS 256
#define NSLOT 64   // stats replication slots (kills atomic hot-spotting)

typedef unsigned short ushort_t;
typedef unsigned int uint_t;

// ---- bf16 <-> f32 helpers (RNE) ----
__device__ __forceinline__ float b2f(ushort_t u) {
    union { float f; uint_t i; } v; v.i = ((uint_t)u) << 16; return v.f;
}
__device__ __forceinline__ ushort_t f2b(float f) {
    uint_t i = __float_as_uint(f);
    uint_t r = i + 0x7fffu + ((i >> 16) & 1u);
    return (ushort_t)(r >> 16);
}
__device__ __forceinline__ void unpack8(uint4 r, float* v) {
    v[0] = b2f(r.x & 0xffff); v[1] = b2f(r.x >> 16);
    v[2] = b2f(r.y & 0xffff); v[3] = b2f(r.y >> 16);
    v[4] = b2f(r.z & 0xffff); v[5] = b2f(r.z >> 16);
    v[6] = b2f(r.w & 0xffff); v[7] = b2f(r.w >> 16);
}
__device__ __forceinline__ uint4 pack8(const float* v) {
    uint4 r;
    r.x = (uint_t)f2b(v[0]) | ((uint_t)f2b(v[1]) << 16);
    r.y = (uint_t)f2b(v[2]) | ((uint_t)f2b(v[3]) << 16);
    r.z = (uint_t)f2b(v[4]) | ((uint_t)f2b(v[5]) << 16);
    r.w = (uint_t)f2b(v[6]) | ((uint_t)f2b(v[7]) << 16);
    return r;
}

// ---------------- small kernels ----------------

__global__ void local_means_kernel(const float* __restrict__ lx,
                                   const int* __restrict__ lt,
                                   float* __restrict__ means, int nl)
{
    int tid = threadIdx.x;
    if (tid >= 7 * 19) return;
    int c = tid / 19, dd = tid % 19;
    float s = 0.f; int cnt = 0;
    for (int i = 0; i < nl; ++i) {
        if (lt[i] == c) { s += lx[i * 19 + dd]; cnt++; }
    }
    means[tid] = cnt > 0 ? s / (float)cnt : 0.f;
}

__global__ void hist_kernel(const int* __restrict__ dst, int* __restrict__ degi, int E)
{
    int t = blockIdx.x * THREADS + threadIdx.x;
    if (t < E) atomicAdd(&degi[dst[t]], 1);
}

// ---- 3-pass parallel exclusive scan over degi ----

__global__ __launch_bounds__(256) void scan_part1_kernel(const int* __restrict__ degi,
                                                         int* __restrict__ blocksums, int n)
{
    const int tid = threadIdx.x;
    const int idx = blockIdx.x * 1024 + tid * 4;
    int v = 0;
    if (idx + 3 < n) {
        int4 d = *(const int4*)&degi[idx];
        v = d.x + d.y + d.z + d.w;
    } else {
        for (int i = 0; i < 4; ++i) if (idx + i < n) v += degi[idx + i];
    }
    __shared__ int s[256];
    s[tid] = v;
    __syncthreads();
    for (int off = 128; off >= 1; off >>= 1) {
        if (tid < off) s[tid] += s[tid + off];
        __syncthreads();
    }
    if (tid == 0) blocksums[blockIdx.x] = s[0];
}

__global__ __launch_bounds__(256) void scan_part2_kernel(int* __restrict__ blocksums, int nb)
{
    __shared__ int s[256];
    const int tid = threadIdx.x;
    int v = (tid < nb) ? blocksums[tid] : 0;
    s[tid] = v;
    __syncthreads();
    for (int off = 1; off < 256; off <<= 1) {
        int t = (tid >= off) ? s[tid - off] : 0;
        __syncthreads();
        s[tid] += t;
        __syncthreads();
    }
    if (tid < nb) blocksums[tid] = s[tid] - v;  // exclusive
}

__global__ __launch_bounds__(256) void scan_part3_kernel(const int* __restrict__ degi,
                                                         const int* __restrict__ blocksums,
                                                         int* __restrict__ rowptr, int n, int E)
{
    const int tid = threadIdx.x;
    const int idx = blockIdx.x * 1024 + tid * 4;
    int d0 = 0, d1 = 0, d2 = 0, d3 = 0;
    if (idx + 3 < n) {
        int4 d = *(const int4*)&degi[idx];
        d0 = d.x; d1 = d.y; d2 = d.z; d3 = d.w;
    } else {
        if (idx     < n) d0 = degi[idx];
        if (idx + 1 < n) d1 = degi[idx + 1];
        if (idx + 2 < n) d2 = degi[idx + 2];
        if (idx + 3 < n) d3 = degi[idx + 3];
    }
    const int v = d0 + d1 + d2 + d3;
    __shared__ int s[256];
    s[tid] = v;
    __syncthreads();
    for (int off = 1; off < 256; off <<= 1) {
        int t = (tid >= off) ? s[tid - off] : 0;
        __syncthreads();
        s[tid] += t;
        __syncthreads();
    }
    int run = blocksums[blockIdx.x] + s[tid] - v;
    if (idx + 3 < n) {
        int4 o;
        o.x = run; run += d0;
        o.y = run; run += d1;
        o.z = run; run += d2;
        o.w = run;
        *(int4*)&rowptr[idx] = o;
    } else {
        if (idx     < n) { rowptr[idx]     = run; run += d0; }
        if (idx + 1 < n) { rowptr[idx + 1] = run; run += d1; }
        if (idx + 2 < n) { rowptr[idx + 2] = run; run += d2; }
        if (idx + 3 < n) { rowptr[idx + 3] = run; }
    }
    if (blockIdx.x == 0 && tid == 0) rowptr[n] = E;
}

__global__ void dinv_kernel(const int* __restrict__ rowptr, float* __restrict__ dinv, int n)
{
    int t = blockIdx.x * THREADS + threadIdx.x;
    if (t < n) dinv[t] = rsqrtf((float)(rowptr[t + 1] - rowptr[t]) + 1.0f);
}

// ---- bucketed CSR fill (2 phases; buckets = 256-node dst ranges) ----

__global__ void bcur_init_kernel(const int* __restrict__ rowptr, int* __restrict__ bcur, int nbk)
{
    int t = blockIdx.x * THREADS + threadIdx.x;
    if (t < nbk) bcur[t] = rowptr[t * 256];
}

__global__ void bucketA_kernel(const int* __restrict__ src, const int* __restrict__ dst,
                               int* __restrict__ bcur, int2* __restrict__ pairs, int E)
{
    int t = blockIdx.x * THREADS + threadIdx.x;
    if (t >= E) return;
    int s = src[t], d = dst[t];
    int pos = atomicAdd(&bcur[d >> 8], 1);
    pairs[pos] = make_int2(s, d);
}

__global__ __launch_bounds__(256) void bucketB_kernel(const int2* __restrict__ pairs,
                                                      const int* __restrict__ rowptr,
                                                      int* __restrict__ esrc, int n)
{
    __shared__ int cur[256];
    const int tid  = threadIdx.x;
    const int base = blockIdx.x * 256;
    const int cnt  = min(256, n - base);
    if (tid < cnt) cur[tid] = rowptr[base + tid];
    __syncthreads();
    const int e0 = rowptr[base];
    const int e1 = rowptr[base + cnt];
    for (int e = e0 + tid; e < e1; e += 256) {
        int2 p = pairs[e];
        int pos = atomicAdd(&cur[p.y - base], 1);
        esrc[pos] = p.x;
    }
}

__global__ void build_x0_kernel(const float* __restrict__ means,
                                const int* __restrict__ vt,
                                const float* __restrict__ vx,
                                const float* __restrict__ label,
                                float* __restrict__ out, int n)
{
    int tid = blockIdx.x * THREADS + threadIdx.x;
    int node = tid >> 5, c = tid & 31;
    if (node >= n) return;
    float v;
    if (c < 19)      v = means[vt[node] * 19 + c];
    else if (c < 25) v = vx[node * 6 + (c - 19)];
    else             v = label[node * 7 + (c - 25)];
    out[(size_t)node * 32 + c] = v;
}

// ---------------- elementwise GN-affine + ReLU + dinv row-scale (f32 in, bf16 out) ----
template<int D>
__global__ void transform_kernel(const float* __restrict__ x, ushort_t* __restrict__ out,
                                 const float* __restrict__ tr, const float* __restrict__ dinv, int n)
{
    constexpr int Q = D / 8;
    int t = blockIdx.x * THREADS + threadIdx.x;
    int node = t / Q, q = t % Q;
    if (node >= n) return;
    float v[8], o[8];
    *(float4*)&v[0] = *(const float4*)&x[(size_t)node * D + q * 8];
    *(float4*)&v[4] = *(const float4*)&x[(size_t)node * D + q * 8 + 4];
    const float dd = dinv[node];
#pragma unroll
    for (int e = 0; e < 8; ++e) {
        o[e] = fmaxf(fmaf(v[e], tr[q * 8 + e], tr[D + q * 8 + e]), 0.f) * dd;
    }
    *(uint4*)&out[(size_t)node * D + q * 8] = pack8(o);
}

// ---------------- dense layer (f32 in, f32 or bf16 out, fp32 math) ----------------
// Split-J tiling: thread's JPER cols live in JQ chunks of 4 at col = q*4*TJ + tj*4.
template<int DIN, int DOUT, int BN, int JPER, bool RELU, bool BIAS, bool TRANSFORM, bool SCALE, bool OUTBF>
__global__ __launch_bounds__(256) void mlp_kernel(
    const float* __restrict__ in, void* __restrict__ out_v,
    const float* __restrict__ W, const float* __restrict__ bias,
    const float* __restrict__ tr /* a[0:DIN), c[DIN:2*DIN) */,
    const float* __restrict__ rowscale, int n)
{
    constexpr int KT  = 32;
    constexpr int TJ  = DOUT / JPER;    // threads along j
    constexpr int TN  = 256 / TJ;       // thread groups along nodes
    constexpr int NPT = BN / TN;        // nodes per thread
    constexpr int JQ  = JPER / 4;       // 4-col chunks per thread
    constexpr int CS  = 4 * TJ;         // chunk stride in cols
    constexpr int BNP = BN + 4;

    __shared__ float Wt[KT * DOUT];
    __shared__ float xT[KT][BNP];

    const int tid   = threadIdx.x;
    const int nbase = blockIdx.x * BN;
    const int tj = tid % TJ, tn = tid / TJ;
    const int j0 = tj * 4, n0 = tn * NPT;

    float acc[NPT][JPER];
#pragma unroll
    for (int p = 0; p < NPT; ++p)
#pragma unroll
        for (int j = 0; j < JPER; ++j) acc[p][j] = 0.f;

    for (int kt = 0; kt < DIN; kt += KT) {
        __syncthreads();
        for (int i = tid * 4; i < KT * DOUT; i += THREADS * 4) {
            *(float4*)&Wt[i] = *(const float4*)&W[(size_t)kt * DOUT + i];
        }
        for (int i = tid; i < BN * (KT / 4); i += THREADS) {
            int node = i / (KT / 4);
            int kq   = i % (KT / 4);
            int g    = nbase + node;
            float4 v = make_float4(0.f, 0.f, 0.f, 0.f);
            if (g < n) {
                v = *(const float4*)&in[(size_t)g * DIN + kt + kq * 4];
                if (TRANSFORM) {
                    const float4 a = *(const float4*)&tr[kt + kq * 4];
                    const float4 c = *(const float4*)&tr[DIN + kt + kq * 4];
                    v.x = fmaxf(fmaf(v.x, a.x, c.x), 0.f);
                    v.y = fmaxf(fmaf(v.y, a.y, c.y), 0.f);
                    v.z = fmaxf(fmaf(v.z, a.z, c.z), 0.f);
                    v.w = fmaxf(fmaf(v.w, a.w, c.w), 0.f);
                }
            }
            xT[kq * 4 + 0][node] = v.x;
            xT[kq * 4 + 1][node] = v.y;
            xT[kq * 4 + 2][node] = v.z;
            xT[kq * 4 + 3][node] = v.w;
        }
        __syncthreads();
#pragma unroll 4
        for (int kk = 0; kk < KT; ++kk) {
            float wv[JPER];
#pragma unroll
            for (int q = 0; q < JQ; ++q)
                *(float4*)&wv[q * 4] = *(const float4*)&Wt[kk * DOUT + q * CS + j0];
            float xv[NPT];
#pragma unroll
            for (int q = 0; q < NPT / 4; ++q)
                *(float4*)&xv[q * 4] = *(const float4*)&xT[kk][n0 + q * 4];
#pragma unroll
            for (int p = 0; p < NPT; ++p)
#pragma unroll
                for (int j = 0; j < JPER; ++j)
                    acc[p][j] = fmaf(xv[p], wv[j], acc[p][j]);
        }
    }

    float bv[JPER];
#pragma unroll
    for (int j = 0; j < JPER; ++j) bv[j] = 0.f;
    if (BIAS) {
#pragma unroll
        for (int q = 0; q < JQ; ++q)
            *(float4*)&bv[q * 4] = *(const float4*)&bias[q * CS + j0];
    }

#pragma unroll
    for (int p = 0; p < NPT; ++p) {
        const int g = nbase + n0 + p;
        if (g >= n) continue;
        float rs = 1.f;
        if (SCALE) rs = rowscale[g];
#pragma unroll
        for (int q = 0; q < JQ; ++q) {
            float o[4];
#pragma unroll
            for (int e = 0; e < 4; ++e) {
                float x = acc[p][q * 4 + e] + bv[q * 4 + e];
                if (RELU) x = fmaxf(x, 0.f);
                if (SCALE) x *= rs;
                o[e] = x;
            }
            if (OUTBF) {
                ushort4 ob;
                ob.x = f2b(o[0]); ob.y = f2b(o[1]); ob.z = f2b(o[2]); ob.w = f2b(o[3]);
                *(ushort4*)&((ushort_t*)out_v)[(size_t)g * DOUT + q * CS + j0] = ob;
            } else {
                *(float4*)&((float*)out_v)[(size_t)g * DOUT + q * CS + j0] =
                    make_float4(o[0], o[1], o[2], o[3]);
            }
        }
    }
}

// ---------------- CSR gather aggregation (post-GEMM), bf16 table -> f32 out ----
template<int D>
__global__ __launch_bounds__(256) void gather_agg_kernel(
    const ushort_t* __restrict__ y, float* __restrict__ out,
    const int* __restrict__ rowptr, const int* __restrict__ esrc,
    const float* __restrict__ dinv,
    const float* __restrict__ bias, float* __restrict__ statsP, int n)
{
    constexpr int JT  = D / 8;       // threads per node
    constexpr int NPB = 256 / JT;    // nodes per block-pass
    const int tid  = threadIdx.x;
    const int jq   = tid % JT;
    const int nsub = tid / JT;
    const int j0   = jq * 8;

    float bv[8];
#pragma unroll
    for (int e = 0; e < 8; ++e) bv[e] = bias[j0 + e];

    float s1[8], s2[8];
#pragma unroll
    for (int e = 0; e < 8; ++e) { s1[e] = 0.f; s2[e] = 0.f; }

    const int ntiles = (n + NPB - 1) / NPB;
    for (int tile = blockIdx.x; tile < ntiles; tile += gridDim.x) {
        const int node = tile * NPB + nsub;
        if (node < n) {
            const int rb = rowptr[node], re = rowptr[node + 1];
            const float dd = dinv[node];
            float acc[8];
            unpack8(*(const uint4*)&y[(size_t)node * D + j0], acc);
            int k = rb;
            for (; k + 3 < re; k += 4) {
                const int sa = esrc[k], sb = esrc[k + 1];
                const int sc = esrc[k + 2], sd = esrc[k + 3];
                const uint4 r0 = *(const uint4*)&y[(size_t)sa * D + j0];
                const uint4 r1 = *(const uint4*)&y[(size_t)sb * D + j0];
                const uint4 r2 = *(const uint4*)&y[(size_t)sc * D + j0];
                const uint4 r3 = *(const uint4*)&y[(size_t)sd * D + j0];
                float v0[8], v1[8], v2[8], v3[8];
                unpack8(r0, v0); unpack8(r1, v1); unpack8(r2, v2); unpack8(r3, v3);
#pragma unroll
                for (int e = 0; e < 8; ++e) acc[e] += (v0[e] + v1[e]) + (v2[e] + v3[e]);
            }
            for (; k < re; ++k) {
                float va[8];
                unpack8(*(const uint4*)&y[(size_t)esrc[k] * D + j0], va);
#pragma unroll
                for (int e = 0; e < 8; ++e) acc[e] += va[e];
            }
            float o[8];
#pragma unroll
            for (int e = 0; e < 8; ++e) {
                o[e] = fmaf(acc[e], dd, bv[e]);
                s1[e] += o[e];
                s2[e] = fmaf(o[e], o[e], s2[e]);
            }
            *(float4*)&out[(size_t)node * D + j0]     = make_float4(o[0], o[1], o[2], o[3]);
            *(float4*)&out[(size_t)node * D + j0 + 4] = make_float4(o[4], o[5], o[6], o[7]);
        }
    }

    __shared__ float red[256][17];
#pragma unroll
    for (int e = 0; e < 8; ++e) { red[tid][e] = s1[e]; red[tid][8 + e] = s2[e]; }
    __syncthreads();
#pragma unroll
    for (int off = NPB / 2; off >= 1; off >>= 1) {
        if (nsub < off) {
#pragma unroll
            for (int e = 0; e < 16; ++e) red[tid][e] += red[tid + off * JT][e];
        }
        __syncthreads();
    }
    if (nsub == 0) {
        float* slot = statsP + (size_t)(blockIdx.x & (NSLOT - 1)) * 256;
#pragma unroll
        for (int e = 0; e < 8; ++e) {
            atomicAdd(&slot[j0 + e],     red[tid][e]);
            atomicAdd(&slot[D + j0 + e], red[tid][8 + e]);
        }
    }
}

// ---------------- CSR gather aggregation (pre-GEMM), bf16 table -> f32 out ----------------
template<int D>
__global__ __launch_bounds__(256) void gather_pre_kernel(
    const ushort_t* __restrict__ x, float* __restrict__ out,
    const int* __restrict__ rowptr, const int* __restrict__ esrc,
    const float* __restrict__ dinv, int n)
{
    constexpr int JT  = D / 8;
    constexpr int NPB = 256 / JT;
    const int tid  = threadIdx.x;
    const int jq   = tid % JT;
    const int nsub = tid / JT;
    const int j0   = jq * 8;

    const int ntiles = (n + NPB - 1) / NPB;
    for (int tile = blockIdx.x; tile < ntiles; tile += gridDim.x) {
        const int node = tile * NPB + nsub;
        if (node < n) {
            const int rb = rowptr[node], re = rowptr[node + 1];
            const float dd = dinv[node];
            float acc[8];
            unpack8(*(const uint4*)&x[(size_t)node * D + j0], acc);
            int k = rb;
            for (; k + 3 < re; k += 4) {
                const int sa = esrc[k], sb = esrc[k + 1];
                const int sc = esrc[k + 2], sd = esrc[k + 3];
                const uint4 r0 = *(const uint4*)&x[(size_t)sa * D + j0];
                const uint4 r1 = *(const uint4*)&x[(size_t)sb * D + j0];
                const uint4 r2 = *(const uint4*)&x[(size_t)sc * D + j0];
                const uint4 r3 = *(const uint4*)&x[(size_t)sd * D + j0];
                float v0[8], v1[8], v2[8], v3[8];
                unpack8(r0, v0); unpack8(r1, v1); unpack8(r2, v2); unpack8(r3, v3);
#pragma unroll
                for (int e = 0; e < 8; ++e) acc[e] += (v0[e] + v1[e]) + (v2[e] + v3[e]);
            }
            for (; k < re; ++k) {
                float va[8];
                unpack8(*(const uint4*)&x[(size_t)esrc[k] * D + j0], va);
#pragma unroll
                for (int e = 0; e < 8; ++e) acc[e] += va[e];
            }
            float o[8];
#pragma unroll
            for (int e = 0; e < 8; ++e) o[e] = acc[e] * dd;
            *(float4*)&out[(size_t)node * D + j0]     = make_float4(o[0], o[1], o[2], o[3]);
            *(float4*)&out[(size_t)node * D + j0 + 4] = make_float4(o[4], o[5], o[6], o[7]);
        }
    }
}

// ---------------- standalone column stats (f32 in) -> slots ----------------
template<int D>
__global__ __launch_bounds__(256) void gn_stats_kernel(const float* __restrict__ x,
                                                       float* __restrict__ statsP, int n)
{
    constexpr int JT   = D / 4;      // col blocks of 4
    constexpr int NPB  = 256 / JT;   // rows in parallel
    constexpr int ITER = 32;
    const int tid  = threadIdx.x;
    const int jb   = tid % JT;
    const int rsub = tid / JT;
    const int j0   = jb * 4;
    const int base = blockIdx.x * NPB * ITER;

    float s1[4] = {0.f, 0.f, 0.f, 0.f};
    float s2[4] = {0.f, 0.f, 0.f, 0.f};

#pragma unroll 4
    for (int i = 0; i < ITER; ++i) {
        int r = base + rsub + i * NPB;
        if (r < n) {
            float4 v = *(const float4*)&x[(size_t)r * D + j0];
            s1[0] += v.x; s1[1] += v.y; s1[2] += v.z; s1[3] += v.w;
            s2[0] = fmaf(v.x, v.x, s2[0]);
            s2[1] = fmaf(v.y, v.y, s2[1]);
            s2[2] = fmaf(v.z, v.z, s2[2]);
            s2[3] = fmaf(v.w, v.w, s2[3]);
        }
    }

    __shared__ float red[256][9];
#pragma unroll
    for (int e = 0; e < 4; ++e) { red[tid][e] = s1[e]; red[tid][4 + e] = s2[e]; }
    __syncthreads();
#pragma unroll
    for (int off = NPB / 2; off >= 1; off >>= 1) {
        if (rsub < off) {
#pragma unroll
            for (int e = 0; e < 8; ++e) red[tid][e] += red[tid + off * JT][e];
        }
        __syncthreads();
    }
    if (rsub == 0) {
        float* slot = statsP + (size_t)(blockIdx.x & (NSLOT - 1)) * 256;
#pragma unroll
        for (int e = 0; e < 4; ++e) {
            atomicAdd(&slot[j0 + e],     red[tid][e]);
            atomicAdd(&slot[D + j0 + e], red[tid][4 + e]);
        }
    }
}

// Reduce slots, turn (sum, sumsq) into the fused affine y = a*x + c
template<int D>
__global__ void gn_finalize_kernel(const float* __restrict__ part, float* __restrict__ ac,
                                   const float* __restrict__ gw, const float* __restrict__ gb,
                                   const float* __restrict__ gm, float inv_n)
{
    int j = threadIdx.x;
    if (j >= D) return;
    float s1 = 0.f, s2 = 0.f;
    for (int t = 0; t < NSLOT; ++t) {
        s1 += part[(size_t)t * 256 + j];
        s2 += part[(size_t)t * 256 + D + j];
    }
    float mean = s1 * inv_n;
    float ex2  = s2 * inv_n;
    float m    = gm[j];
    float var  = ex2 - (2.f * m - m * m) * mean * mean;
    float a    = gw[j] * rsqrtf(var + 1e-5f);
    float c    = gb[j] - a * m * mean;
    ac[j]     = a;
    ac[D + j] = c;
}

// ---------------- fused decoder tail: 64 -> relu32 -> relu16 -> sigmoid(1) ----------------
// One node per thread; x row in registers; W via uniform-index loads (scalarized).
__global__ __launch_bounds__(256) void dec_tail_kernel(
    const float* __restrict__ in, const float* __restrict__ W1, const float* __restrict__ b1,
    const float* __restrict__ W2, const float* __restrict__ b2,
    const float* __restrict__ W3, const float* __restrict__ b3,
    float* __restrict__ out, int n)
{
    int t = blockIdx.x * THREADS + threadIdx.x;
    if (t >= n) return;

    float x[64];
#pragma unroll
    for (int q = 0; q < 16; ++q)
        *(float4*)&x[q * 4] = *(const float4*)&in[(size_t)t * 64 + q * 4];

    float h1[32];
#pragma unroll
    for (int j = 0; j < 32; ++j) h1[j] = b1[j];
#pragma unroll 8
    for (int k = 0; k < 64; ++k) {
        const float xk = x[k];
#pragma unroll
        for (int j = 0; j < 32; ++j) h1[j] = fmaf(xk, W1[k * 32 + j], h1[j]);
    }
#pragma unroll
    for (int j = 0; j < 32; ++j) h1[j] = fmaxf(h1[j], 0.f);

    float h2[16];
#pragma unroll
    for (int j = 0; j < 16; ++j) h2[j] = b2[j];
#pragma unroll 8
    for (int k = 0; k < 32; ++k) {
        const float hk = h1[k];
#pragma unroll
        for (int j = 0; j < 16; ++j) h2[j] = fmaf(hk, W2[k * 16 + j], h2[j]);
    }

    float acc = b3[0];
#pragma unroll
    for (int k = 0; k < 16; ++k) acc = fmaf(fmaxf(h2[k], 0.f), W3[k], acc);
    out[t] = 1.0f / (1.0f + expf(-acc));
}

// ---------------- launch ----------------

extern "C" void kernel_launch(void* const* d_in, const int* in_sizes, int n_in,
                              void* d_out, int out_size, void* d_ws, size_t ws_size,
                              hipStream_t stream)
{
    const float* local_x    = (const float*)d_in[0];
    const int*   local_type = (const int*)d_in[1];
    const float* voxel_x    = (const float*)d_in[2];
    const int*   voxel_type = (const int*)d_in[3];
    const int*   edge_index = (const int*)d_in[4];
    const float* label      = (const float*)d_in[5];
    const float* We1 = (const float*)d_in[6],  *be1 = (const float*)d_in[7];
    const float* We2 = (const float*)d_in[8],  *be2 = (const float*)d_in[9];
    const float *Wc[4], *bc[4], *gw[4], *gb[4], *gm[4];
    for (int i = 0; i < 4; ++i) {
        Wc[i] = (const float*)d_in[10 + i * 5];
        bc[i] = (const float*)d_in[11 + i * 5];
        gw[i] = (const float*)d_in[12 + i * 5];
        gb[i] = (const float*)d_in[13 + i * 5];
        gm[i] = (const float*)d_in[14 + i * 5];
    }
    const float* Wd0 = (const float*)d_in[30], *bd0 = (const float*)d_in[31];
    const float* Wd1 = (const float*)d_in[32], *bd1 = (const float*)d_in[33];
    const float* Wd2 = (const float*)d_in[34], *bd2 = (const float*)d_in[35];
    const float* Wd3 = (const float*)d_in[36], *bd3 = (const float*)d_in[37];

    const int n  = in_sizes[2] / 6;    // 200000
    const int E  = in_sizes[4] / 2;    // 1200000
    const int nl = in_sizes[0] / 19;   // 400
    const int* src = edge_index;
    const int* dst = edge_index + E;

    // Workspace (~247 MB, < proven-safe 257 MB):
    // [ac 4KB][means 4KB][blocksums 1KB][bcur 4KB][stats_part 256KB][rowptr n+1][dinv n]
    // [esrc E][pairs E*8B][A f32 n*128][B f32 n*128][Y bf16 n*64]
    auto align256 = [](size_t x) { return (x + 255) & ~(size_t)255; };
    char* w = (char*)d_ws;
    float* ac_all = (float*)w;
    float* means  = (float*)(w + 4096);
    int* blocksums = (int*)(w + 8192);
    int* bcur      = (int*)(w + 8192 + 1024);
    float* stats_part = (float*)(w + 8192 + 1024 + 4096);
    size_t off = 8192 + 1024 + 4096 + 4 * NSLOT * 256 * sizeof(float);
    int*   rowptr = (int*)(w + off);   off += align256((size_t)(n + 1) * 4);
    float* dinv   = (float*)(w + off); off += align256((size_t)n * 4);
    int*   esrc   = (int*)(w + off);   off += align256((size_t)E * 4);
    int2*  pairs  = (int2*)(w + off);  off += align256((size_t)E * 8);
    float* A  = (float*)(w + off);                 // n*128 f32
    float* B  = A + (size_t)n * 128;               // n*128 f32
    ushort_t* Y = (ushort_t*)(B + (size_t)n * 128); // n*64 bf16 gather table
    float* A2 = A + (size_t)n * 64;
    float* B2 = B + (size_t)n * 64;
    int*   degi = (int*)A;                          // transient alias

    const float inv_n = 1.0f / (float)n;
    auto cdiv = [](long long a, long long b) { return (int)((a + b - 1) / b); };
    const int nb  = cdiv(n, 1024);
    const int nbk = cdiv(n, 256);   // 782 fill buckets

    float* part0 = stats_part + 0 * NSLOT * 256;
    float* part1 = stats_part + 1 * NSLOT * 256;
    float* part2 = stats_part + 2 * NSLOT * 256;
    float* part3 = stats_part + 3 * NSLOT * 256;
    float* ac0 = ac_all + 0, *ac1 = ac_all + 256, *ac2 = ac_all + 512, *ac3 = ac_all + 768;

    hipMemsetAsync(stats_part, 0, 4 * NSLOT * 256 * sizeof(float), stream);
    hipMemsetAsync(degi, 0, (size_t)n * sizeof(int), stream);

    local_means_kernel<<<1, 192, 0, stream>>>(local_x, local_type, means, nl);
    hist_kernel<<<cdiv(E, 256), 256, 0, stream>>>(dst, degi, E);
    scan_part1_kernel<<<nb, 256, 0, stream>>>(degi, blocksums, n);
    scan_part2_kernel<<<1, 256, 0, stream>>>(blocksums, nb);
    scan_part3_kernel<<<nb, 256, 0, stream>>>(degi, blocksums, rowptr, n, E);
    dinv_kernel<<<cdiv(n, 256), 256, 0, stream>>>(rowptr, dinv, n);
    bcur_init_kernel<<<cdiv(nbk, 256), 256, 0, stream>>>(rowptr, bcur, nbk);
    bucketA_kernel<<<cdiv(E, 256), 256, 0, stream>>>(src, dst, bcur, pairs, E);
    bucketB_kernel<<<nbk, 256, 0, stream>>>(pairs, rowptr, esrc, n);
    build_x0_kernel<<<cdiv((long long)n * 32, 256), 256, 0, stream>>>(means, voxel_type, voxel_x, label, B, n);

    const int gagg = 2048;

    // encoder: B(32) -> A(128) -> B(128)   [all f32]
    mlp_kernel<32, 128, 256, 16, true, true, false, false, false><<<cdiv(n, 256), 256, 0, stream>>>(B, A, We1, be1, nullptr, nullptr, n);
    mlp_kernel<128, 128, 256, 16, true, true, false, false, false><<<cdiv(n, 256), 256, 0, stream>>>(A, B, We2, be2, nullptr, nullptr, n);

    // conv0 (128->64, agg post-GEMM): B -> Y(bf16, dinv-scaled) -> agg A2(f32) [+stats0]
    mlp_kernel<128, 64, 256, 8, false, false, false, true, true><<<cdiv(n, 256), 256, 0, stream>>>(B, Y, Wc[0], nullptr, nullptr, dinv, n);
    gather_agg_kernel<64><<<gagg, 256, 0, stream>>>(Y, A2, rowptr, esrc, dinv, bc[0], part0, n);
    gn_finalize_kernel<64><<<1, 64, 0, stream>>>(part0, ac0, gw[0], gb[0], gm[0], inv_n);

    // conv1 (64->32, agg post-GEMM): A2(+GN) -> Y(bf16 32w) -> agg B2(f32) [+stats1]
    mlp_kernel<64, 32, 256, 4, false, false, true, true, true><<<cdiv(n, 256), 256, 0, stream>>>(A2, Y, Wc[1], nullptr, ac0, dinv, n);
    gather_agg_kernel<32><<<gagg, 256, 0, stream>>>(Y, B2, rowptr, esrc, dinv, bc[1], part1, n);
    gn_finalize_kernel<32><<<1, 32, 0, stream>>>(part1, ac1, gw[1], gb[1], gm[1], inv_n);

    // conv2 (32->64, agg PRE-GEMM): B2(+GN) -> Y(bf16 32w) -> agg A(f32 32w) -> GEMM A2(64) -> stats2
    transform_kernel<32><<<cdiv((long long)n * 4, 256), 256, 0, stream>>>(B2, Y, ac1, dinv, n);
    gather_pre_kernel<32><<<gagg, 256, 0, stream>>>(Y, A, rowptr, esrc, dinv, n);
    mlp_kernel<32, 64, 256, 8, false, true, false, false, false><<<cdiv(n, 256), 256, 0, stream>>>(A, A2, Wc[2], bc[2], nullptr, nullptr, n);
    gn_stats_kernel<64><<<cdiv(n, 512), 256, 0, stream>>>(A2, part2, n);
    gn_finalize_kernel<64><<<1, 64, 0, stream>>>(part2, ac2, gw[2], gb[2], gm[2], inv_n);

    // conv3 (64->128, agg PRE-GEMM): A2(+GN) -> Y(bf16 64w) -> agg B(f32 64w) -> GEMM A(128) -> stats3
    transform_kernel<64><<<cdiv((long long)n * 8, 256), 256, 0, stream>>>(A2, Y, ac2, dinv, n);
    gather_pre_kernel<64><<<gagg, 256, 0, stream>>>(Y, B, rowptr, esrc, dinv, n);
    mlp_kernel<64, 128, 256, 16, false, true, false, false, false><<<cdiv(n, 256), 256, 0, stream>>>(B, A, Wc[3], bc[3], nullptr, nullptr, n);
    gn_stats_kernel<128><<<cdiv(n, 256), 256, 0, stream>>>(A, part3, n);
    gn_finalize_kernel<128><<<1, 128, 0, stream>>>(part3, ac3, gw[3], gb[3], gm[3], inv_n);

    // decoder: A(128,+GN) -> B(64) -> fused tail -> out
    mlp_kernel<128, 64, 256, 8, true, true, true, false, false><<<cdiv(n, 256), 256, 0, stream>>>(A, B, Wd0, bd0, ac3, nullptr, n);
    dec_tail_kernel<<<cdiv(n, 256), 256, 0, stream>>>(B, Wd1, bd1, Wd2, bd2, Wd3, bd3, (float*)d_out, n);
}

// Round 10
// 812.073 us; speedup vs baseline: 1.3750x; 1.3750x over previous
//
#include <hip/hip_runtime.h>
#include <hip/hip_bf16.h>
#include <cstddef>

#define THREADS 256
#define NSLOT 64   // stats replication slots (kills atomic hot-spotting)

typedef unsigned short ushort_t;
typedef unsigned int uint_t;

// ---- bf16 <-> f32 helpers (RNE) ----
__device__ __forceinline__ float b2f(ushort_t u) {
    union { float f; uint_t i; } v; v.i = ((uint_t)u) << 16; return v.f;
}
__device__ __forceinline__ ushort_t f2b(float f) {
    uint_t i = __float_as_uint(f);
    uint_t r = i + 0x7fffu + ((i >> 16) & 1u);
    return (ushort_t)(r >> 16);
}
__device__ __forceinline__ void unpack8(uint4 r, float* v) {
    v[0] = b2f(r.x & 0xffff); v[1] = b2f(r.x >> 16);
    v[2] = b2f(r.y & 0xffff); v[3] = b2f(r.y >> 16);
    v[4] = b2f(r.z & 0xffff); v[5] = b2f(r.z >> 16);
    v[6] = b2f(r.w & 0xffff); v[7] = b2f(r.w >> 16);
}
__device__ __forceinline__ uint4 pack8(const float* v) {
    uint4 r;
    r.x = (uint_t)f2b(v[0]) | ((uint_t)f2b(v[1]) << 16);
    r.y = (uint_t)f2b(v[2]) | ((uint_t)f2b(v[3]) << 16);
    r.z = (uint_t)f2b(v[4]) | ((uint_t)f2b(v[5]) << 16);
    r.w = (uint_t)f2b(v[6]) | ((uint_t)f2b(v[7]) << 16);
    return r;
}

// ---------------- small kernels ----------------

// LDS-staged per-class mean of local_x (nl <= 512)
__global__ __launch_bounds__(256) void local_means_kernel(const float* __restrict__ lx,
                                                          const int* __restrict__ lt,
                                                          float* __restrict__ means, int nl)
{
    __shared__ float slx[512 * 19];
    __shared__ int   slt[512];
    const int tid = threadIdx.x;
    for (int i = tid; i < nl * 19; i += 256) slx[i] = lx[i];
    for (int i = tid; i < nl; i += 256) slt[i] = lt[i];
    __syncthreads();
    if (tid >= 7 * 19) return;
    int c = tid / 19, dd = tid % 19;
    float s = 0.f; int cnt = 0;
    for (int i = 0; i < nl; ++i) {
        if (slt[i] == c) { s += slx[i * 19 + dd]; cnt++; }
    }
    means[tid] = cnt > 0 ? s / (float)cnt : 0.f;
}

__global__ void hist_kernel(const int* __restrict__ dst, int* __restrict__ degi, int E)
{
    int t = blockIdx.x * THREADS + threadIdx.x;
    if (t < E) atomicAdd(&degi[dst[t]], 1);
}

// ---- 3-pass parallel exclusive scan over degi ----

__global__ __launch_bounds__(256) void scan_part1_kernel(const int* __restrict__ degi,
                                                         int* __restrict__ blocksums, int n)
{
    const int tid = threadIdx.x;
    const int idx = blockIdx.x * 1024 + tid * 4;
    int v = 0;
    if (idx + 3 < n) {
        int4 d = *(const int4*)&degi[idx];
        v = d.x + d.y + d.z + d.w;
    } else {
        for (int i = 0; i < 4; ++i) if (idx + i < n) v += degi[idx + i];
    }
    __shared__ int s[256];
    s[tid] = v;
    __syncthreads();
    for (int off = 128; off >= 1; off >>= 1) {
        if (tid < off) s[tid] += s[tid + off];
        __syncthreads();
    }
    if (tid == 0) blocksums[blockIdx.x] = s[0];
}

__global__ __launch_bounds__(256) void scan_part2_kernel(int* __restrict__ blocksums, int nb)
{
    __shared__ int s[256];
    const int tid = threadIdx.x;
    int v = (tid < nb) ? blocksums[tid] : 0;
    s[tid] = v;
    __syncthreads();
    for (int off = 1; off < 256; off <<= 1) {
        int t = (tid >= off) ? s[tid - off] : 0;
        __syncthreads();
        s[tid] += t;
        __syncthreads();
    }
    if (tid < nb) blocksums[tid] = s[tid] - v;  // exclusive
}

// writes rowptr + cursor copy + dinv (fused)
__global__ __launch_bounds__(256) void scan_part3_kernel(const int* __restrict__ degi,
                                                         const int* __restrict__ blocksums,
                                                         int* __restrict__ rowptr,
                                                         int* __restrict__ cursor,
                                                         float* __restrict__ dinv, int n, int E)
{
    const int tid = threadIdx.x;
    const int idx = blockIdx.x * 1024 + tid * 4;
    int d0 = 0, d1 = 0, d2 = 0, d3 = 0;
    if (idx + 3 < n) {
        int4 d = *(const int4*)&degi[idx];
        d0 = d.x; d1 = d.y; d2 = d.z; d3 = d.w;
    } else {
        if (idx     < n) d0 = degi[idx];
        if (idx + 1 < n) d1 = degi[idx + 1];
        if (idx + 2 < n) d2 = degi[idx + 2];
        if (idx + 3 < n) d3 = degi[idx + 3];
    }
    const int v = d0 + d1 + d2 + d3;
    __shared__ int s[256];
    s[tid] = v;
    __syncthreads();
    for (int off = 1; off < 256; off <<= 1) {
        int t = (tid >= off) ? s[tid - off] : 0;
        __syncthreads();
        s[tid] += t;
        __syncthreads();
    }
    int run = blocksums[blockIdx.x] + s[tid] - v;
    if (idx + 3 < n) {
        int4 o;
        o.x = run; run += d0;
        o.y = run; run += d1;
        o.z = run; run += d2;
        o.w = run;
        *(int4*)&rowptr[idx] = o;
        *(int4*)&cursor[idx] = o;
        float4 dv;
        dv.x = rsqrtf((float)d0 + 1.0f);
        dv.y = rsqrtf((float)d1 + 1.0f);
        dv.z = rsqrtf((float)d2 + 1.0f);
        dv.w = rsqrtf((float)d3 + 1.0f);
        *(float4*)&dinv[idx] = dv;
    } else {
        if (idx     < n) { rowptr[idx]     = run; cursor[idx]     = run; dinv[idx]     = rsqrtf((float)d0 + 1.0f); run += d0; }
        if (idx + 1 < n) { rowptr[idx + 1] = run; cursor[idx + 1] = run; dinv[idx + 1] = rsqrtf((float)d1 + 1.0f); run += d1; }
        if (idx + 2 < n) { rowptr[idx + 2] = run; cursor[idx + 2] = run; dinv[idx + 2] = rsqrtf((float)d2 + 1.0f); run += d2; }
        if (idx + 3 < n) { rowptr[idx + 3] = run; cursor[idx + 3] = run; dinv[idx + 3] = rsqrtf((float)d3 + 1.0f); }
    }
    if (blockIdx.x == 0 && tid == 0) rowptr[n] = E;
}

__global__ void fill_kernel(const int* __restrict__ src, const int* __restrict__ dst,
                            int* __restrict__ cursor, int* __restrict__ esrc, int E)
{
    int t = blockIdx.x * THREADS + threadIdx.x;
    if (t >= E) return;
    int s = src[t], d = dst[t];
    int pos = atomicAdd(&cursor[d], 1);
    esrc[pos] = s;
}

__global__ void build_x0_kernel(const float* __restrict__ means,
                                const int* __restrict__ vt,
                                const float* __restrict__ vx,
                                const float* __restrict__ label,
                                float* __restrict__ out, int n)
{
    int tid = blockIdx.x * THREADS + threadIdx.x;
    int node = tid >> 5, c = tid & 31;
    if (node >= n) return;
    float v;
    if (c < 19)      v = means[vt[node] * 19 + c];
    else if (c < 25) v = vx[node * 6 + (c - 19)];
    else             v = label[node * 7 + (c - 25)];
    out[(size_t)node * 32 + c] = v;
}

// ---------------- elementwise GN-affine + ReLU + dinv row-scale (f32 in, bf16 out) ----
template<int D>
__global__ void transform_kernel(const float* __restrict__ x, ushort_t* __restrict__ out,
                                 const float* __restrict__ tr, const float* __restrict__ dinv, int n)
{
    constexpr int Q = D / 8;
    int t = blockIdx.x * THREADS + threadIdx.x;
    int node = t / Q, q = t % Q;
    if (node >= n) return;
    float v[8], o[8];
    *(float4*)&v[0] = *(const float4*)&x[(size_t)node * D + q * 8];
    *(float4*)&v[4] = *(const float4*)&x[(size_t)node * D + q * 8 + 4];
    const float dd = dinv[node];
#pragma unroll
    for (int e = 0; e < 8; ++e) {
        o[e] = fmaxf(fmaf(v[e], tr[q * 8 + e], tr[D + q * 8 + e]), 0.f) * dd;
    }
    *(uint4*)&out[(size_t)node * D + q * 8] = pack8(o);
}

// ---------------- dense layer (f32 in, f32 or bf16 out, fp32 math) ----------------
// Split-J tiling: thread's JPER cols live in JQ chunks of 4 at col = q*4*TJ + tj*4.
template<int DIN, int DOUT, int BN, int JPER, bool RELU, bool BIAS, bool TRANSFORM, bool SCALE, bool OUTBF>
__global__ __launch_bounds__(256) void mlp_kernel(
    const float* __restrict__ in, void* __restrict__ out_v,
    const float* __restrict__ W, const float* __restrict__ bias,
    const float* __restrict__ tr /* a[0:DIN), c[DIN:2*DIN) */,
    const float* __restrict__ rowscale, int n)
{
    constexpr int KT  = 32;
    constexpr int TJ  = DOUT / JPER;    // threads along j
    constexpr int TN  = 256 / TJ;       // thread groups along nodes
    constexpr int NPT = BN / TN;        // nodes per thread
    constexpr int JQ  = JPER / 4;       // 4-col chunks per thread
    constexpr int CS  = 4 * TJ;         // chunk stride in cols
    constexpr int BNP = BN + 4;

    __shared__ float Wt[KT * DOUT];
    __shared__ float xT[KT][BNP];

    const int tid   = threadIdx.x;
    const int nbase = blockIdx.x * BN;
    const int tj = tid % TJ, tn = tid / TJ;
    const int j0 = tj * 4, n0 = tn * NPT;

    float acc[NPT][JPER];
#pragma unroll
    for (int p = 0; p < NPT; ++p)
#pragma unroll
        for (int j = 0; j < JPER; ++j) acc[p][j] = 0.f;

    for (int kt = 0; kt < DIN; kt += KT) {
        __syncthreads();
        for (int i = tid * 4; i < KT * DOUT; i += THREADS * 4) {
            *(float4*)&Wt[i] = *(const float4*)&W[(size_t)kt * DOUT + i];
        }
        for (int i = tid; i < BN * (KT / 4); i += THREADS) {
            int node = i / (KT / 4);
            int kq   = i % (KT / 4);
            int g    = nbase + node;
            float4 v = make_float4(0.f, 0.f, 0.f, 0.f);
            if (g < n) {
                v = *(const float4*)&in[(size_t)g * DIN + kt + kq * 4];
                if (TRANSFORM) {
                    const float4 a = *(const float4*)&tr[kt + kq * 4];
                    const float4 c = *(const float4*)&tr[DIN + kt + kq * 4];
                    v.x = fmaxf(fmaf(v.x, a.x, c.x), 0.f);
                    v.y = fmaxf(fmaf(v.y, a.y, c.y), 0.f);
                    v.z = fmaxf(fmaf(v.z, a.z, c.z), 0.f);
                    v.w = fmaxf(fmaf(v.w, a.w, c.w), 0.f);
                }
            }
            xT[kq * 4 + 0][node] = v.x;
            xT[kq * 4 + 1][node] = v.y;
            xT[kq * 4 + 2][node] = v.z;
            xT[kq * 4 + 3][node] = v.w;
        }
        __syncthreads();
#pragma unroll 4
        for (int kk = 0; kk < KT; ++kk) {
            float wv[JPER];
#pragma unroll
            for (int q = 0; q < JQ; ++q)
                *(float4*)&wv[q * 4] = *(const float4*)&Wt[kk * DOUT + q * CS + j0];
            float xv[NPT];
#pragma unroll
            for (int q = 0; q < NPT / 4; ++q)
                *(float4*)&xv[q * 4] = *(const float4*)&xT[kk][n0 + q * 4];
#pragma unroll
            for (int p = 0; p < NPT; ++p)
#pragma unroll
                for (int j = 0; j < JPER; ++j)
                    acc[p][j] = fmaf(xv[p], wv[j], acc[p][j]);
        }
    }

    float bv[JPER];
#pragma unroll
    for (int j = 0; j < JPER; ++j) bv[j] = 0.f;
    if (BIAS) {
#pragma unroll
        for (int q = 0; q < JQ; ++q)
            *(float4*)&bv[q * 4] = *(const float4*)&bias[q * CS + j0];
    }

#pragma unroll
    for (int p = 0; p < NPT; ++p) {
        const int g = nbase + n0 + p;
        if (g >= n) continue;
        float rs = 1.f;
        if (SCALE) rs = rowscale[g];
#pragma unroll
        for (int q = 0; q < JQ; ++q) {
            float o[4];
#pragma unroll
            for (int e = 0; e < 4; ++e) {
                float x = acc[p][q * 4 + e] + bv[q * 4 + e];
                if (RELU) x = fmaxf(x, 0.f);
                if (SCALE) x *= rs;
                o[e] = x;
            }
            if (OUTBF) {
                ushort4 ob;
                ob.x = f2b(o[0]); ob.y = f2b(o[1]); ob.z = f2b(o[2]); ob.w = f2b(o[3]);
                *(ushort4*)&((ushort_t*)out_v)[(size_t)g * DOUT + q * CS + j0] = ob;
            } else {
                *(float4*)&((float*)out_v)[(size_t)g * DOUT + q * CS + j0] =
                    make_float4(o[0], o[1], o[2], o[3]);
            }
        }
    }
}

// ---------------- CSR gather aggregation (post-GEMM), bf16 table -> f32 out ----
template<int D>
__global__ __launch_bounds__(256) void gather_agg_kernel(
    const ushort_t* __restrict__ y, float* __restrict__ out,
    const int* __restrict__ rowptr, const int* __restrict__ esrc,
    const float* __restrict__ dinv,
    const float* __restrict__ bias, float* __restrict__ statsP, int n)
{
    constexpr int JT  = D / 8;       // threads per node
    constexpr int NPB = 256 / JT;    // nodes per block-pass
    const int tid  = threadIdx.x;
    const int jq   = tid % JT;
    const int nsub = tid / JT;
    const int j0   = jq * 8;

    float bv[8];
#pragma unroll
    for (int e = 0; e < 8; ++e) bv[e] = bias[j0 + e];

    float s1[8], s2[8];
#pragma unroll
    for (int e = 0; e < 8; ++e) { s1[e] = 0.f; s2[e] = 0.f; }

    const int ntiles = (n + NPB - 1) / NPB;
    for (int tile = blockIdx.x; tile < ntiles; tile += gridDim.x) {
        const int node = tile * NPB + nsub;
        if (node < n) {
            const int rb = rowptr[node], re = rowptr[node + 1];
            const float dd = dinv[node];
            float acc[8];
            unpack8(*(const uint4*)&y[(size_t)node * D + j0], acc);
            int k = rb;
            for (; k + 3 < re; k += 4) {
                const int sa = esrc[k], sb = esrc[k + 1];
                const int sc = esrc[k + 2], sd = esrc[k + 3];
                const uint4 r0 = *(const uint4*)&y[(size_t)sa * D + j0];
                const uint4 r1 = *(const uint4*)&y[(size_t)sb * D + j0];
                const uint4 r2 = *(const uint4*)&y[(size_t)sc * D + j0];
                const uint4 r3 = *(const uint4*)&y[(size_t)sd * D + j0];
                float v0[8], v1[8], v2[8], v3[8];
                unpack8(r0, v0); unpack8(r1, v1); unpack8(r2, v2); unpack8(r3, v3);
#pragma unroll
                for (int e = 0; e < 8; ++e) acc[e] += (v0[e] + v1[e]) + (v2[e] + v3[e]);
            }
            for (; k < re; ++k) {
                float va[8];
                unpack8(*(const uint4*)&y[(size_t)esrc[k] * D + j0], va);
#pragma unroll
                for (int e = 0; e < 8; ++e) acc[e] += va[e];
            }
            float o[8];
#pragma unroll
            for (int e = 0; e < 8; ++e) {
                o[e] = fmaf(acc[e], dd, bv[e]);
                s1[e] += o[e];
                s2[e] = fmaf(o[e], o[e], s2[e]);
            }
            *(float4*)&out[(size_t)node * D + j0]     = make_float4(o[0], o[1], o[2], o[3]);
            *(float4*)&out[(size_t)node * D + j0 + 4] = make_float4(o[4], o[5], o[6], o[7]);
        }
    }

    __shared__ float red[256][17];
#pragma unroll
    for (int e = 0; e < 8; ++e) { red[tid][e] = s1[e]; red[tid][8 + e] = s2[e]; }
    __syncthreads();
#pragma unroll
    for (int off = NPB / 2; off >= 1; off >>= 1) {
        if (nsub < off) {
#pragma unroll
            for (int e = 0; e < 16; ++e) red[tid][e] += red[tid + off * JT][e];
        }
        __syncthreads();
    }
    if (nsub == 0) {
        float* slot = statsP + (size_t)(blockIdx.x & (NSLOT - 1)) * 256;
#pragma unroll
        for (int e = 0; e < 8; ++e) {
            atomicAdd(&slot[j0 + e],     red[tid][e]);
            atomicAdd(&slot[D + j0 + e], red[tid][8 + e]);
        }
    }
}

// ---------------- CSR gather aggregation (pre-GEMM), bf16 table -> f32 out ----------------
template<int D>
__global__ __launch_bounds__(256) void gather_pre_kernel(
    const ushort_t* __restrict__ x, float* __restrict__ out,
    const int* __restrict__ rowptr, const int* __restrict__ esrc,
    const float* __restrict__ dinv, int n)
{
    constexpr int JT  = D / 8;
    constexpr int NPB = 256 / JT;
    const int tid  = threadIdx.x;
    const int jq   = tid % JT;
    const int nsub = tid / JT;
    const int j0   = jq * 8;

    const int ntiles = (n + NPB - 1) / NPB;
    for (int tile = blockIdx.x; tile < ntiles; tile += gridDim.x) {
        const int node = tile * NPB + nsub;
        if (node < n) {
            const int rb = rowptr[node], re = rowptr[node + 1];
            const float dd = dinv[node];
            float acc[8];
            unpack8(*(const uint4*)&x[(size_t)node * D + j0], acc);
            int k = rb;
            for (; k + 3 < re; k += 4) {
                const int sa = esrc[k], sb = esrc[k + 1];
                const int sc = esrc[k + 2], sd = esrc[k + 3];
                const uint4 r0 = *(const uint4*)&x[(size_t)sa * D + j0];
                const uint4 r1 = *(const uint4*)&x[(size_t)sb * D + j0];
                const uint4 r2 = *(const uint4*)&x[(size_t)sc * D + j0];
                const uint4 r3 = *(const uint4*)&x[(size_t)sd * D + j0];
                float v0[8], v1[8], v2[8], v3[8];
                unpack8(r0, v0); unpack8(r1, v1); unpack8(r2, v2); unpack8(r3, v3);
#pragma unroll
                for (int e = 0; e < 8; ++e) acc[e] += (v0[e] + v1[e]) + (v2[e] + v3[e]);
            }
            for (; k < re; ++k) {
                float va[8];
                unpack8(*(const uint4*)&x[(size_t)esrc[k] * D + j0], va);
#pragma unroll
                for (int e = 0; e < 8; ++e) acc[e] += va[e];
            }
            float o[8];
#pragma unroll
            for (int e = 0; e < 8; ++e) o[e] = acc[e] * dd;
            *(float4*)&out[(size_t)node * D + j0]     = make_float4(o[0], o[1], o[2], o[3]);
            *(float4*)&out[(size_t)node * D + j0 + 4] = make_float4(o[4], o[5], o[6], o[7]);
        }
    }
}

// ---------------- standalone column stats (f32 in) -> slots ----------------
template<int D>
__global__ __launch_bounds__(256) void gn_stats_kernel(const float* __restrict__ x,
                                                       float* __restrict__ statsP, int n)
{
    constexpr int JT   = D / 4;      // col blocks of 4
    constexpr int NPB  = 256 / JT;   // rows in parallel
    constexpr int ITER = 32;
    const int tid  = threadIdx.x;
    const int jb   = tid % JT;
    const int rsub = tid / JT;
    const int j0   = jb * 4;
    const int base = blockIdx.x * NPB * ITER;

    float s1[4] = {0.f, 0.f, 0.f, 0.f};
    float s2[4] = {0.f, 0.f, 0.f, 0.f};

#pragma unroll 4
    for (int i = 0; i < ITER; ++i) {
        int r = base + rsub + i * NPB;
        if (r < n) {
            float4 v = *(const float4*)&x[(size_t)r * D + j0];
            s1[0] += v.x; s1[1] += v.y; s1[2] += v.z; s1[3] += v.w;
            s2[0] = fmaf(v.x, v.x, s2[0]);
            s2[1] = fmaf(v.y, v.y, s2[1]);
            s2[2] = fmaf(v.z, v.z, s2[2]);
            s2[3] = fmaf(v.w, v.w, s2[3]);
        }
    }

    __shared__ float red[256][9];
#pragma unroll
    for (int e = 0; e < 4; ++e) { red[tid][e] = s1[e]; red[tid][4 + e] = s2[e]; }
    __syncthreads();
#pragma unroll
    for (int off = NPB / 2; off >= 1; off >>= 1) {
        if (rsub < off) {
#pragma unroll
            for (int e = 0; e < 8; ++e) red[tid][e] += red[tid + off * JT][e];
        }
        __syncthreads();
    }
    if (rsub == 0) {
        float* slot = statsP + (size_t)(blockIdx.x & (NSLOT - 1)) * 256;
#pragma unroll
        for (int e = 0; e < 4; ++e) {
            atomicAdd(&slot[j0 + e],     red[tid][e]);
            atomicAdd(&slot[D + j0 + e], red[tid][4 + e]);
        }
    }
}

// Reduce slots, turn (sum, sumsq) into the fused affine y = a*x + c
template<int D>
__global__ void gn_finalize_kernel(const float* __restrict__ part, float* __restrict__ ac,
                                   const float* __restrict__ gw, const float* __restrict__ gb,
                                   const float* __restrict__ gm, float inv_n)
{
    int j = threadIdx.x;
    if (j >= D) return;
    float s1 = 0.f, s2 = 0.f;
    for (int t = 0; t < NSLOT; ++t) {
        s1 += part[(size_t)t * 256 + j];
        s2 += part[(size_t)t * 256 + D + j];
    }
    float mean = s1 * inv_n;
    float ex2  = s2 * inv_n;
    float m    = gm[j];
    float var  = ex2 - (2.f * m - m * m) * mean * mean;
    float a    = gw[j] * rsqrtf(var + 1e-5f);
    float c    = gb[j] - a * m * mean;
    ac[j]     = a;
    ac[D + j] = c;
}

// ---------------- fused decoder tail: 64 -> relu32 -> relu16 -> sigmoid(1) ----------------
__global__ __launch_bounds__(256) void dec_tail_kernel(
    const float* __restrict__ in, const float* __restrict__ W1, const float* __restrict__ b1,
    const float* __restrict__ W2, const float* __restrict__ b2,
    const float* __restrict__ W3, const float* __restrict__ b3,
    float* __restrict__ out, int n)
{
    int t = blockIdx.x * THREADS + threadIdx.x;
    if (t >= n) return;

    float x[64];
#pragma unroll
    for (int q = 0; q < 16; ++q)
        *(float4*)&x[q * 4] = *(const float4*)&in[(size_t)t * 64 + q * 4];

    float h1[32];
#pragma unroll
    for (int j = 0; j < 32; ++j) h1[j] = b1[j];
#pragma unroll 8
    for (int k = 0; k < 64; ++k) {
        const float xk = x[k];
#pragma unroll
        for (int j = 0; j < 32; ++j) h1[j] = fmaf(xk, W1[k * 32 + j], h1[j]);
    }
#pragma unroll
    for (int j = 0; j < 32; ++j) h1[j] = fmaxf(h1[j], 0.f);

    float h2[16];
#pragma unroll
    for (int j = 0; j < 16; ++j) h2[j] = b2[j];
#pragma unroll 8
    for (int k = 0; k < 32; ++k) {
        const float hk = h1[k];
#pragma unroll
        for (int j = 0; j < 16; ++j) h2[j] = fmaf(hk, W2[k * 16 + j], h2[j]);
    }

    float acc = b3[0];
#pragma unroll
    for (int k = 0; k < 16; ++k) acc = fmaf(fmaxf(h2[k], 0.f), W3[k], acc);
    out[t] = 1.0f / (1.0f + expf(-acc));
}

// ---------------- launch ----------------

extern "C" void kernel_launch(void* const* d_in, const int* in_sizes, int n_in,
                              void* d_out, int out_size, void* d_ws, size_t ws_size,
                              hipStream_t stream)
{
    const float* local_x    = (const float*)d_in[0];
    const int*   local_type = (const int*)d_in[1];
    const float* voxel_x    = (const float*)d_in[2];
    const int*   voxel_type = (const int*)d_in[3];
    const int*   edge_index = (const int*)d_in[4];
    const float* label      = (const float*)d_in[5];
    const float* We1 = (const float*)d_in[6],  *be1 = (const float*)d_in[7];
    const float* We2 = (const float*)d_in[8],  *be2 = (const float*)d_in[9];
    const float *Wc[4], *bc[4], *gw[4], *gb[4], *gm[4];
    for (int i = 0; i < 4; ++i) {
        Wc[i] = (const float*)d_in[10 + i * 5];
        bc[i] = (const float*)d_in[11 + i * 5];
        gw[i] = (const float*)d_in[12 + i * 5];
        gb[i] = (const float*)d_in[13 + i * 5];
        gm[i] = (const float*)d_in[14 + i * 5];
    }
    const float* Wd0 = (const float*)d_in[30], *bd0 = (const float*)d_in[31];
    const float* Wd1 = (const float*)d_in[32], *bd1 = (const float*)d_in[33];
    const float* Wd2 = (const float*)d_in[34], *bd2 = (const float*)d_in[35];
    const float* Wd3 = (const float*)d_in[36], *bd3 = (const float*)d_in[37];

    const int n  = in_sizes[2] / 6;    // 200000
    const int E  = in_sizes[4] / 2;    // 1200000
    const int nl = in_sizes[0] / 19;   // 400
    const int* src = edge_index;
    const int* dst = edge_index + E;

    // Workspace (~237 MB, < proven-safe 257 MB):
    // [ac 4KB][means 4KB][blocksums 1KB][stats_part 256KB][rowptr n+1][dinv n][esrc E]
    // [A f32 n*128][B f32 n*128][Y bf16 n*64]; transient degi/cursor alias A.
    auto align256 = [](size_t x) { return (x + 255) & ~(size_t)255; };
    char* w = (char*)d_ws;
    float* ac_all = (float*)w;
    float* means  = (float*)(w + 4096);
    int* blocksums = (int*)(w + 8192);
    float* stats_part = (float*)(w + 8192 + 1024);
    size_t off = 8192 + 1024 + 4 * NSLOT * 256 * sizeof(float);
    int*   rowptr = (int*)(w + off);   off += align256((size_t)(n + 1) * 4);
    float* dinv   = (float*)(w + off); off += align256((size_t)n * 4);
    int*   esrc   = (int*)(w + off);   off += align256((size_t)E * 4);
    float* A  = (float*)(w + off);                 // n*128 f32
    float* B  = A + (size_t)n * 128;               // n*128 f32
    ushort_t* Y = (ushort_t*)(B + (size_t)n * 128); // n*64 bf16 gather table
    float* A2 = A + (size_t)n * 64;
    float* B2 = B + (size_t)n * 64;
    int*   degi   = (int*)A;                        // transient alias
    int*   cursor = (int*)A2;                       // transient alias

    const float inv_n = 1.0f / (float)n;
    auto cdiv = [](long long a, long long b) { return (int)((a + b - 1) / b); };
    const int nb = cdiv(n, 1024);

    float* part0 = stats_part + 0 * NSLOT * 256;
    float* part1 = stats_part + 1 * NSLOT * 256;
    float* part2 = stats_part + 2 * NSLOT * 256;
    float* part3 = stats_part + 3 * NSLOT * 256;
    float* ac0 = ac_all + 0, *ac1 = ac_all + 256, *ac2 = ac_all + 512, *ac3 = ac_all + 768;

    hipMemsetAsync(stats_part, 0, 4 * NSLOT * 256 * sizeof(float), stream);
    hipMemsetAsync(degi, 0, (size_t)n * sizeof(int), stream);

    local_means_kernel<<<1, 256, 0, stream>>>(local_x, local_type, means, nl);
    hist_kernel<<<cdiv(E, 256), 256, 0, stream>>>(dst, degi, E);
    scan_part1_kernel<<<nb, 256, 0, stream>>>(degi, blocksums, n);
    scan_part2_kernel<<<1, 256, 0, stream>>>(blocksums, nb);
    scan_part3_kernel<<<nb, 256, 0, stream>>>(degi, blocksums, rowptr, cursor, dinv, n, E);
    fill_kernel<<<cdiv(E, 256), 256, 0, stream>>>(src, dst, cursor, esrc, E);
    build_x0_kernel<<<cdiv((long long)n * 32, 256), 256, 0, stream>>>(means, voxel_type, voxel_x, label, B, n);

    const int gagg = 2048;

    // encoder: B(32) -> A(128) -> B(128)   [all f32]
    mlp_kernel<32, 128, 128, 8, true, true, false, false, false><<<cdiv(n, 128), 256, 0, stream>>>(B, A, We1, be1, nullptr, nullptr, n);
    mlp_kernel<128, 128, 128, 8, true, true, false, false, false><<<cdiv(n, 128), 256, 0, stream>>>(A, B, We2, be2, nullptr, nullptr, n);

    // conv0 (128->64, agg post-GEMM): B -> Y(bf16, dinv-scaled) -> agg A2(f32) [+stats0]
    mlp_kernel<128, 64, 256, 8, false, false, false, true, true><<<cdiv(n, 256), 256, 0, stream>>>(B, Y, Wc[0], nullptr, nullptr, dinv, n);
    gather_agg_kernel<64><<<gagg, 256, 0, stream>>>(Y, A2, rowptr, esrc, dinv, bc[0], part0, n);
    gn_finalize_kernel<64><<<1, 64, 0, stream>>>(part0, ac0, gw[0], gb[0], gm[0], inv_n);

    // conv1 (64->32, agg post-GEMM): A2(+GN) -> Y(bf16 32w) -> agg B2(f32) [+stats1]
    mlp_kernel<64, 32, 256, 4, false, false, true, true, true><<<cdiv(n, 256), 256, 0, stream>>>(A2, Y, Wc[1], nullptr, ac0, dinv, n);
    gather_agg_kernel<32><<<gagg, 256, 0, stream>>>(Y, B2, rowptr, esrc, dinv, bc[1], part1, n);
    gn_finalize_kernel<32><<<1, 32, 0, stream>>>(part1, ac1, gw[1], gb[1], gm[1], inv_n);

    // conv2 (32->64, agg PRE-GEMM): B2(+GN) -> Y(bf16 32w) -> agg A(f32 32w) -> GEMM A2(64) -> stats2
    transform_kernel<32><<<cdiv((long long)n * 4, 256), 256, 0, stream>>>(B2, Y, ac1, dinv, n);
    gather_pre_kernel<32><<<gagg, 256, 0, stream>>>(Y, A, rowptr, esrc, dinv, n);
    mlp_kernel<32, 64, 256, 8, false, true, false, false, false><<<cdiv(n, 256), 256, 0, stream>>>(A, A2, Wc[2], bc[2], nullptr, nullptr, n);
    gn_stats_kernel<64><<<cdiv(n, 512), 256, 0, stream>>>(A2, part2, n);
    gn_finalize_kernel<64><<<1, 64, 0, stream>>>(part2, ac2, gw[2], gb[2], gm[2], inv_n);

    // conv3 (64->128, agg PRE-GEMM): A2(+GN) -> Y(bf16 64w) -> agg B(f32 64w) -> GEMM A(128) -> stats3
    transform_kernel<64><<<cdiv((long long)n * 8, 256), 256, 0, stream>>>(A2, Y, ac2, dinv, n);
    gather_pre_kernel<64><<<gagg, 256, 0, stream>>>(Y, B, rowptr, esrc, dinv, n);
    mlp_kernel<64, 128, 128, 8, false, true, false, false, false><<<cdiv(n, 128), 256, 0, stream>>>(B, A, Wc[3], bc[3], nullptr, nullptr, n);
    gn_stats_kernel<128><<<cdiv(n, 256), 256, 0, stream>>>(A, part3, n);
    gn_finalize_kernel<128><<<1, 128, 0, stream>>>(part3, ac3, gw[3], gb[3], gm[3], inv_n);

    // decoder: A(128,+GN) -> B(64) -> fused tail -> out
    mlp_kernel<128, 64, 256, 8, true, true, true, false, false><<<cdiv(n, 256), 256, 0, stream>>>(A, B, Wd0, bd0, ac3, nullptr, n);
    dec_tail_kernel<<<cdiv(n, 256), 256, 0, stream>>>(B, Wd1, bd1, Wd2, bd2, Wd3, bd3, (float*)d_out, n);
}